// Round 3
// baseline (150.428 us; speedup 1.0000x reference)
//
#include <hip/hip_runtime.h>

#define HH 512
#define WW 512
#define TS 32
#define SQH 42
#define SQW 44   /* 42 used + 2 pad so (row*44 + 4*k) is 16B-aligned */
#define SQU 42   /* used width */
#define O1H 39
#define O1W 39
#define O2H 35
#define O2W 35

__global__ __launch_bounds__(256) void enc_fused(
    const float* __restrict__ f,
    const float* __restrict__ w1, const float* __restrict__ b1,
    const float* __restrict__ w2, const float* __restrict__ b2,
    const float* __restrict__ w3, const float* __restrict__ b3,
    const float* __restrict__ w4, const float* __restrict__ b4,
    float* __restrict__ out)
{
    __shared__ __align__(16) float s_sq[SQH*SQW];
    __shared__ __align__(16) float s_o1[O1H*O1W*2];   // [h][w][c2]
    __shared__ __align__(16) float s_o2[O2H*O2W*4];   // [h][w][c4]
    __shared__ __align__(16) float s_w2t[108];        // [tap9][ci3][c4]
    __shared__ __align__(16) float s_w3t[224];        // [tap4][ci7][c8] (sq chans folded)
    __shared__ __align__(16) float s_w4t[240];        // [u15][c16]      (dups folded)
    __shared__ float s_b2[4], s_b3[8], s_b4[16];

    const int tid = threadIdx.x;
    const int b  = blockIdx.z;
    const int h0 = blockIdx.y * TS;
    const int w0 = blockIdx.x * TS;

    // ---- stage weights, transposed + duplicate-channel folding ----
    for (int t = tid; t < 108; t += 256) {
        int c = t & 3, ci = (t >> 2) % 3, tap = t / 12;
        int i = tap / 3, j = tap % 3;
        s_w2t[t] = w2[((c*3+ci)*3+i)*3+j];
    }
    for (int t = tid; t < 224; t += 256) {
        int c = t & 7, ci = (t >> 3) % 7, tap = t / 56;
        int i = tap >> 1, j = tap & 1;
        float v = w3[((c*8+ci)*2+i)*2+j];
        if (ci == 6) v += w3[((c*8+7)*2+i)*2+j];   // o2cat ch6,7 both = sq
        s_w3t[t] = v;
    }
    for (int t = tid; t < 240; t += 256) {
        int c = t & 15, u = t >> 4;
        float v;
        if (u < 12)       v = w4[c*20+u];                                    // o3 0-7, o2 8-11
        else if (u == 12) v = w4[c*20+12] + w4[c*20+16];                     // o1_0
        else if (u == 13) v = w4[c*20+13] + w4[c*20+17];                     // o1_1
        else              v = w4[c*20+14] + w4[c*20+15] + w4[c*20+18] + w4[c*20+19]; // sq
        s_w4t[t] = v;
    }
    if (tid < 4)                s_b2[tid]    = b2[tid];
    if (tid >= 32 && tid < 40)  s_b3[tid-32] = b3[tid-32];
    if (tid >= 64 && tid < 80)  s_b4[tid-64] = b4[tid-64];

    // ---- sq: wrapped vertical diff, squared (diff(unwrap) == local wrap) ----
    const float* fb = f + (size_t)b * (HH*WW);
    const float PI = 3.14159265358979323846f;
    const float TWO_PI = 6.283185307179586477f;
    #pragma unroll
    for (int p = 0; p < 7; ++p) {
        int idx = tid + 256*p;
        if (idx < SQH*SQU) {
            int rh = idx / SQU, rw = idx % SQU;
            int gh = h0 + rh - 4, gw = w0 + rw - 4;
            float v = 0.f;
            if (gh > 0 && gh < HH && gw >= 0 && gw < WW) {
                float d = fb[gh*WW + gw] - fb[(gh-1)*WW + gw];
                float m = fmodf(d + PI, TWO_PI);
                if (m < 0.f) m += TWO_PI;
                float dd = m - PI;
                if (dd == -PI && d > 0.f) dd = PI;
                float r = (fabsf(d) < PI) ? d : dd;
                v = r * r;
            }
            s_sq[rh*SQW + rw] = v;
        }
    }
    __syncthreads();

    // ---- o1: 4x4 dil1 (pad l1/r2), 1ch -> 2ch; OOB positions forced to 0 ----
    #pragma unroll
    for (int p = 0; p < 6; ++p) {
        int idx = tid + 256*p;
        if (idx < O1H*O1W) {
            int rh = idx / O1W, rw = idx % O1W;
            float a0 = b1[0], a1 = b1[1];
            #pragma unroll
            for (int i = 0; i < 4; ++i)
            #pragma unroll
            for (int j = 0; j < 4; ++j) {
                float x = s_sq[(rh+i)*SQW + rw+j];
                a0 += x * w1[i*4+j];
                a1 += x * w1[16+i*4+j];
            }
            int gy = h0 + rh - 3, gx = w0 + rw - 3;
            bool inimg = (gy >= 0) & (gy < HH) & (gx >= 0) & (gx < WW);
            float2 o; o.x = inimg ? a0 : 0.f; o.y = inimg ? a1 : 0.f;
            *(float2*)&s_o1[idx*2] = o;
        }
    }
    __syncthreads();

    // ---- o2: 3x3 dil2 (pad 2/2), 3ch -> 4ch; OOB positions forced to 0 ----
    {
        int rh[5], rw[5]; bool val[5], img[5];
        float acc[4][5];
        #pragma unroll
        for (int p = 0; p < 5; ++p) {
            int idx = tid + 256*p;
            val[p] = idx < O2H*O2W;
            int id = val[p] ? idx : 0;
            rh[p] = id / O2W; rw[p] = id % O2W;
            int gy = h0 + rh[p] - 1, gx = w0 + rw[p] - 1;
            img[p] = (gy >= 0) & (gy < HH) & (gx >= 0) & (gx < WW);
            #pragma unroll
            for (int c = 0; c < 4; ++c) acc[c][p] = s_b2[c];
        }
        #pragma unroll
        for (int i = 0; i < 3; ++i)
        #pragma unroll
        for (int j = 0; j < 3; ++j) {
            const float* wt = &s_w2t[(i*3+j)*12];
            const float4 wa = *(const float4*)&wt[0];
            const float4 wb = *(const float4*)&wt[4];
            const float4 wc = *(const float4*)&wt[8];
            #pragma unroll
            for (int p = 0; p < 5; ++p) {
                float2 xo = *(const float2*)&s_o1[((rh[p]+2*i)*O1W + rw[p]+2*j)*2];
                float  xs = s_sq[(rh[p]+1+2*i)*SQW + rw[p]+1+2*j];
                acc[0][p] += xo.x*wa.x + xo.y*wb.x + xs*wc.x;
                acc[1][p] += xo.x*wa.y + xo.y*wb.y + xs*wc.y;
                acc[2][p] += xo.x*wa.z + xo.y*wb.z + xs*wc.z;
                acc[3][p] += xo.x*wa.w + xo.y*wb.w + xs*wc.w;
            }
        }
        #pragma unroll
        for (int p = 0; p < 5; ++p) if (val[p]) {
            float4 o;
            o.x = img[p] ? acc[0][p] : 0.f;
            o.y = img[p] ? acc[1][p] : 0.f;
            o.z = img[p] ? acc[2][p] : 0.f;
            o.w = img[p] ? acc[3][p] : 0.f;
            *(float4*)&s_o2[(rh[p]*O2W + rw[p])*4] = o;
        }
    }
    __syncthreads();

    // ---- o3: 2x2 dil3 (pad 1/2) 8->8; o4: 1x1 15u->16; float4 stores (1 row x 4 cols/thread) ----
    {
        const int wq = tid & 7;      // w group (0..7)
        const int hq = tid >> 3;     // row (0..31)
        const int c0 = wq * 4;       // local w of px0

        float sqa[4], o1a[2][4], o2a[4][4], o3v[8][4];
        {
            const float4 s4 = *(const float4*)&s_sq[(hq+4)*SQW + c0+4];  // aligned by SQW=44
            sqa[0]=s4.x; sqa[1]=s4.y; sqa[2]=s4.z; sqa[3]=s4.w;
            #pragma unroll
            for (int p = 0; p < 4; ++p) {
                float2 t2 = *(const float2*)&s_o1[((hq+3)*O1W + c0+3+p)*2];
                o1a[0][p]=t2.x; o1a[1][p]=t2.y;
                float4 t4 = *(const float4*)&s_o2[((hq+1)*O2W + c0+1+p)*4];
                o2a[0][p]=t4.x; o2a[1][p]=t4.y; o2a[2][p]=t4.z; o2a[3][p]=t4.w;
            }
        }
        #pragma unroll
        for (int c = 0; c < 8; ++c) {
            float bv = s_b3[c];
            #pragma unroll
            for (int p = 0; p < 4; ++p) o3v[c][p] = bv;
        }
        #pragma unroll
        for (int i = 0; i < 2; ++i)
        #pragma unroll
        for (int j = 0; j < 2; ++j) {
            float xin[7][4];
            #pragma unroll
            for (int p = 0; p < 4; ++p) {
                float4 a = *(const float4*)&s_o2[((hq+3*i)*O2W + c0+p+3*j)*4];
                xin[0][p]=a.x; xin[1][p]=a.y; xin[2][p]=a.z; xin[3][p]=a.w;
                float2 bq = *(const float2*)&s_o1[((hq+3*i+2)*O1W + c0+p+3*j+2)*2];
                xin[4][p]=bq.x; xin[5][p]=bq.y;
                xin[6][p]=s_sq[(hq+3*i+3)*SQW + c0+p+3*j+3];
            }
            const float* wt = &s_w3t[(i*2+j)*56];
            #pragma unroll
            for (int ci = 0; ci < 7; ++ci) {
                float4 wa = *(const float4*)&wt[ci*8];
                float4 wb = *(const float4*)&wt[ci*8+4];
                #pragma unroll
                for (int p = 0; p < 4; ++p) {
                    float x = xin[ci][p];
                    o3v[0][p] += x*wa.x; o3v[1][p] += x*wa.y;
                    o3v[2][p] += x*wa.z; o3v[3][p] += x*wa.w;
                    o3v[4][p] += x*wb.x; o3v[5][p] += x*wb.y;
                    o3v[6][p] += x*wb.z; o3v[7][p] += x*wb.w;
                }
            }
        }
        const size_t HWp = (size_t)HH*WW;
        float* ob = out + (size_t)b*48*HWp + (size_t)(h0 + hq)*WW + (w0 + c0);

        #pragma unroll
        for (int cg = 0; cg < 4; ++cg) {
            float acc[4][4];
            #pragma unroll
            for (int c = 0; c < 4; ++c) {
                float bv = s_b4[cg*4+c];
                #pragma unroll
                for (int p = 0; p < 4; ++p) acc[c][p] = bv;
            }
            #pragma unroll
            for (int u = 0; u < 15; ++u) {
                float4 wv = *(const float4*)&s_w4t[u*16 + cg*4];
                #pragma unroll
                for (int p = 0; p < 4; ++p) {
                    float x = (u<8) ? o3v[u][p] : (u<12) ? o2a[u-8][p]
                            : (u<14) ? o1a[u-12][p] : sqa[p];
                    acc[0][p]+=x*wv.x; acc[1][p]+=x*wv.y;
                    acc[2][p]+=x*wv.z; acc[3][p]+=x*wv.w;
                }
            }
            #pragma unroll
            for (int c = 0; c < 4; ++c) {
                float4 o; o.x=acc[c][0]; o.y=acc[c][1]; o.z=acc[c][2]; o.w=acc[c][3];
                *(float4*)&ob[(size_t)(cg*4+c)*HWp] = o;
            }
        }
        float4 vsq; vsq.x=sqa[0]; vsq.y=sqa[1]; vsq.z=sqa[2]; vsq.w=sqa[3];
        float4 vo1a; vo1a.x=o1a[0][0]; vo1a.y=o1a[0][1]; vo1a.z=o1a[0][2]; vo1a.w=o1a[0][3];
        float4 vo1b; vo1b.x=o1a[1][0]; vo1b.y=o1a[1][1]; vo1b.z=o1a[1][2]; vo1b.w=o1a[1][3];
        #pragma unroll
        for (int c = 0; c < 8; ++c) {
            float4 o; o.x=o3v[c][0]; o.y=o3v[c][1]; o.z=o3v[c][2]; o.w=o3v[c][3];
            *(float4*)&ob[(size_t)(16+c)*HWp] = o;
        }
        #pragma unroll
        for (int c = 0; c < 4; ++c) {
            float4 o; o.x=o2a[c][0]; o.y=o2a[c][1]; o.z=o2a[c][2]; o.w=o2a[c][3];
            *(float4*)&ob[(size_t)(24+c)*HWp] = o;
            *(float4*)&ob[(size_t)(36+c)*HWp] = o;
        }
        *(float4*)&ob[28*HWp]=vo1a; *(float4*)&ob[29*HWp]=vo1b;
        *(float4*)&ob[30*HWp]=vsq;  *(float4*)&ob[31*HWp]=vsq;
        *(float4*)&ob[32*HWp]=vo1a; *(float4*)&ob[33*HWp]=vo1b;
        *(float4*)&ob[34*HWp]=vsq;  *(float4*)&ob[35*HWp]=vsq;
        *(float4*)&ob[40*HWp]=vo1a; *(float4*)&ob[41*HWp]=vo1b;
        *(float4*)&ob[42*HWp]=vsq;  *(float4*)&ob[43*HWp]=vsq;
        *(float4*)&ob[44*HWp]=vo1a; *(float4*)&ob[45*HWp]=vo1b;
        *(float4*)&ob[46*HWp]=vsq;  *(float4*)&ob[47*HWp]=vsq;
    }
}

extern "C" void kernel_launch(void* const* d_in, const int* in_sizes, int n_in,
                              void* d_out, int out_size, void* d_ws, size_t ws_size,
                              hipStream_t stream) {
    const float* f  = (const float*)d_in[0];
    const float* w1 = (const float*)d_in[1];
    const float* b1 = (const float*)d_in[2];
    const float* w2 = (const float*)d_in[3];
    const float* b2 = (const float*)d_in[4];
    const float* w3 = (const float*)d_in[5];
    const float* b3 = (const float*)d_in[6];
    const float* w4 = (const float*)d_in[7];
    const float* b4 = (const float*)d_in[8];
    float* out = (float*)d_out;

    dim3 grid(WW/TS, HH/TS, 8);
    enc_fused<<<grid, 256, 0, stream>>>(f, w1, b1, w2, b2, w3, b3, w4, b4, out);
}